// Round 1
// baseline (929.148 us; speedup 1.0000x reference)
//
#include <hip/hip_runtime.h>

#define N_NODES   50000
#define N_EDGES   1600000
#define N_GRAPHS  512
#define IN_C      16
#define H1        64
#define H2        64
#define H3        128
#define OUT_C     10

// ---------------- degree / norm ----------------

__global__ void k_init_deg(float* __restrict__ deg) {
    int i = blockIdx.x * blockDim.x + threadIdx.x;
    if (i < N_NODES) deg[i] = 1.0f;   // self-loop
}

__global__ void k_deg_edges(const int* __restrict__ dst, float* __restrict__ deg) {
    int e = blockIdx.x * blockDim.x + threadIdx.x;
    if (e < N_EDGES) atomicAdd(&deg[dst[e]], 1.0f);
}

__global__ void k_dinv(float* __restrict__ deg) {
    int i = blockIdx.x * blockDim.x + threadIdx.x;
    if (i < N_NODES) deg[i] = rsqrtf(deg[i]);   // in-place: deg -> deg^-1/2
}

// ---------------- layer GEMMs ----------------
// hw[n][c] = sum_k x[n][k] * W[k][c]   (thread per output element; lanes share node)

__global__ void k_gemm1(const float* __restrict__ x, const float* __restrict__ W,
                        float* __restrict__ hw) {
    int t = blockIdx.x * blockDim.x + threadIdx.x;
    int n = t >> 6, c = t & 63;
    if (n >= N_NODES) return;
    const float* xr = x + n * IN_C;
    float acc = 0.f;
#pragma unroll
    for (int k = 0; k < IN_C; ++k) acc += xr[k] * W[k * H1 + c];
    hw[t] = acc;
}

// in = pre-activation layer-1 output; apply ReLU on load.
__global__ void k_gemm2(const float* __restrict__ in, const float* __restrict__ W,
                        float* __restrict__ hw) {
    int t = blockIdx.x * blockDim.x + threadIdx.x;
    int n = t >> 6, c = t & 63;
    if (n >= N_NODES) return;
    const float* r = in + n * H1;
    float acc = 0.f;
#pragma unroll
    for (int k = 0; k < H1; ++k) acc += fmaxf(r[k], 0.f) * W[k * H2 + c];
    hw[t] = acc;
}

// ---------------- aggregation ----------------
// out[n][c] = b[c] + hw[n][c] * dinv[n]^2   (bias + self-loop message)

__global__ void k_init_out(const float* __restrict__ hw, const float* __restrict__ dinv,
                           const float* __restrict__ b, float* __restrict__ out) {
    int t = blockIdx.x * blockDim.x + threadIdx.x;
    int n = t >> 6, c = t & 63;
    if (n >= N_NODES) return;
    float di = dinv[n];
    out[t] = b[c] + hw[t] * di * di;
}

// per-(edge,channel) thread: out[dst][c] += hw[src][c] * dinv[src]*dinv[dst]
__global__ void k_agg(const int* __restrict__ src, const int* __restrict__ dst,
                      const float* __restrict__ dinv, const float* __restrict__ hw,
                      float* __restrict__ out) {
    int t = blockIdx.x * blockDim.x + threadIdx.x;
    int e = t >> 6, c = t & 63;
    if (e >= N_EDGES) return;
    int s = src[e], d = dst[e];
    float norm = dinv[s] * dinv[d];
    atomicAdd(&out[d * 64 + c], hw[s * 64 + c] * norm);
}

// ---------------- pooling ----------------

__global__ void k_pool_zero(float* __restrict__ pool, float* __restrict__ cnt) {
    int i = blockIdx.x * blockDim.x + threadIdx.x;
    if (i < N_GRAPHS * H2) pool[i] = 0.f;
    if (i < N_GRAPHS) cnt[i] = 0.f;
}

__global__ void k_count(const int* __restrict__ batch, float* __restrict__ cnt) {
    int n = blockIdx.x * blockDim.x + threadIdx.x;
    if (n < N_NODES) atomicAdd(&cnt[batch[n]], 1.0f);
}

__global__ void k_pool(const int* __restrict__ batch, const float* __restrict__ h,
                       float* __restrict__ pool) {
    int t = blockIdx.x * blockDim.x + threadIdx.x;
    int n = t >> 6, c = t & 63;
    if (n >= N_NODES) return;
    atomicAdd(&pool[batch[n] * H2 + c], fmaxf(h[t], 0.f));
}

// ---------------- MLP head (one block per graph) ----------------

__global__ void __launch_bounds__(128)
k_mlp(const float* __restrict__ pool, const float* __restrict__ cnt,
      const float* __restrict__ Wf1, const float* __restrict__ bf1,
      const float* __restrict__ Wf2, const float* __restrict__ bf2,
      float* __restrict__ out) {
    int g = blockIdx.x;
    int tid = threadIdx.x;
    __shared__ float p[H2];
    __shared__ float tbuf[H3];
    float inv = 1.0f / fmaxf(cnt[g], 1.0f);
    if (tid < H2) p[tid] = pool[g * H2 + tid] * inv;
    __syncthreads();
    {
        float acc = bf1[tid];
#pragma unroll
        for (int k = 0; k < H2; ++k) acc += p[k] * Wf1[k * H3 + tid];
        tbuf[tid] = acc;   // NOTE: reference has NO ReLU between Wf1 and Wf2
    }
    __syncthreads();
    if (tid < OUT_C) {
        float acc = bf2[tid];
#pragma unroll
        for (int m = 0; m < H3; ++m) acc += tbuf[m] * Wf2[m * OUT_C + tid];
        out[g * OUT_C + tid] = acc;
    }
}

// ---------------- launch ----------------

extern "C" void kernel_launch(void* const* d_in, const int* in_sizes, int n_in,
                              void* d_out, int out_size, void* d_ws, size_t ws_size,
                              hipStream_t stream) {
    const float* x    = (const float*)d_in[0];
    const int*   ei   = (const int*)  d_in[1];   // [2, E] row-major
    const int*   batch= (const int*)  d_in[2];
    const float* W1   = (const float*)d_in[3];
    const float* b1   = (const float*)d_in[4];
    const float* W2   = (const float*)d_in[5];
    const float* b2   = (const float*)d_in[6];
    const float* Wf1  = (const float*)d_in[7];
    const float* bf1  = (const float*)d_in[8];
    const float* Wf2  = (const float*)d_in[9];
    const float* bf2  = (const float*)d_in[10];
    float* out = (float*)d_out;

    const int* src = ei;            // edge_index[0]
    const int* dst = ei + N_EDGES;  // edge_index[1]

    // workspace layout (all 256-B aligned)
    char* ws = (char*)d_ws;
    size_t off = 0;
    auto alloc = [&](size_t bytes) {
        char* p = ws + off;
        off += (bytes + 255) & ~size_t(255);
        return p;
    };
    float* dinv = (float*)alloc(N_NODES * sizeof(float));
    float* bufA = (float*)alloc((size_t)N_NODES * 64 * sizeof(float));
    float* bufB = (float*)alloc((size_t)N_NODES * 64 * sizeof(float));
    float* pool = (float*)alloc(N_GRAPHS * H2 * sizeof(float));
    float* cnt  = (float*)alloc(N_GRAPHS * sizeof(float));
    (void)ws_size;

    const int BLK = 256;
    int gN   = (N_NODES + BLK - 1) / BLK;
    int gE   = (N_EDGES + BLK - 1) / BLK;
    int gNC  = (N_NODES * 64 + BLK - 1) / BLK;
    int gEC  = (int)(((long long)N_EDGES * 64 + BLK - 1) / BLK);

    // degrees -> dinv
    k_init_deg <<<gN, BLK, 0, stream>>>(dinv);
    k_deg_edges<<<gE, BLK, 0, stream>>>(dst, dinv);
    k_dinv     <<<gN, BLK, 0, stream>>>(dinv);

    // layer 1: hw1 = x@W1 (bufA); out1 = b1 + self + scatter (bufB)
    k_gemm1   <<<gNC, BLK, 0, stream>>>(x, W1, bufA);
    k_init_out<<<gNC, BLK, 0, stream>>>(bufA, dinv, b1, bufB);
    k_agg     <<<gEC, BLK, 0, stream>>>(src, dst, dinv, bufA, bufB);

    // layer 2: hw2 = relu(out1)@W2 (bufA, hw1 dead); out2 = b2 + self + scatter (bufB, out1 dead)
    k_gemm2   <<<gNC, BLK, 0, stream>>>(bufB, W2, bufA);
    k_init_out<<<gNC, BLK, 0, stream>>>(bufA, dinv, b2, bufB);
    k_agg     <<<gEC, BLK, 0, stream>>>(src, dst, dinv, bufA, bufB);

    // global mean pool of relu(out2)
    int gP = (N_GRAPHS * H2 + BLK - 1) / BLK;
    k_pool_zero<<<gP, BLK, 0, stream>>>(pool, cnt);
    k_count    <<<gN, BLK, 0, stream>>>(batch, cnt);
    k_pool     <<<gNC, BLK, 0, stream>>>(batch, bufB, pool);

    // MLP head
    k_mlp<<<N_GRAPHS, 128, 0, stream>>>(pool, cnt, Wf1, bf1, Wf2, bf2, out);
}

// Round 2
// 486.579 us; speedup vs baseline: 1.9096x; 1.9096x over previous
//
#include <hip/hip_runtime.h>

#define N_NODES   50000
#define N_EDGES   1600000
#define N_GRAPHS  512
#define IN_C      16
#define H1        64
#define H2        64
#define H3        128
#define OUT_C     10

// ---------------- CSR build: histogram / scan / scatter ----------------

__global__ void k_zero2(int* __restrict__ cnt, int* __restrict__ fill) {
    int i = blockIdx.x * blockDim.x + threadIdx.x;
    if (i < N_NODES) { cnt[i] = 0; fill[i] = 0; }
}

__global__ void k_hist(const int* __restrict__ dst, int* __restrict__ cnt) {
    int e = blockIdx.x * blockDim.x + threadIdx.x;
    if (e < N_EDGES) atomicAdd(&cnt[dst[e]], 1);
}

// dinv[i] = rsqrt(in_degree + 1 self-loop)
__global__ void k_dinv(const int* __restrict__ cnt, float* __restrict__ dinv) {
    int i = blockIdx.x * blockDim.x + threadIdx.x;
    if (i < N_NODES) dinv[i] = rsqrtf((float)(cnt[i] + 1));
}

// single-block exclusive scan of cnt[N_NODES] -> rowoff[N_NODES+1]
__global__ void __launch_bounds__(1024) k_scan(const int* __restrict__ cnt,
                                               int* __restrict__ rowoff) {
    __shared__ int buf[1024];
    __shared__ int base;
    if (threadIdx.x == 0) base = 0;
    __syncthreads();
    for (int start = 0; start < N_NODES; start += 1024) {
        int i = start + (int)threadIdx.x;
        int v = (i < N_NODES) ? cnt[i] : 0;
        buf[threadIdx.x] = v;
        __syncthreads();
        for (int s = 1; s < 1024; s <<= 1) {
            int t = (threadIdx.x >= (unsigned)s) ? buf[threadIdx.x - s] : 0;
            __syncthreads();
            buf[threadIdx.x] += t;
            __syncthreads();
        }
        int incl = buf[threadIdx.x];
        if (i < N_NODES) rowoff[i] = base + incl - v;   // exclusive
        __syncthreads();                                 // all reads of base done
        if (threadIdx.x == 1023) base += incl;           // chunk total
        __syncthreads();
    }
    if (threadIdx.x == 0) rowoff[N_NODES] = base;
}

__global__ void k_scatter(const int* __restrict__ src, const int* __restrict__ dst,
                          const int* __restrict__ rowoff, int* __restrict__ fill,
                          int* __restrict__ src_sorted) {
    int e = blockIdx.x * blockDim.x + threadIdx.x;
    if (e >= N_EDGES) return;
    int d = dst[e];
    int pos = rowoff[d] + atomicAdd(&fill[d], 1);
    src_sorted[pos] = src[e];
}

// ---------------- layer GEMMs ----------------

__global__ void k_gemm1(const float* __restrict__ x, const float* __restrict__ W,
                        float* __restrict__ hw) {
    int t = blockIdx.x * blockDim.x + threadIdx.x;
    int n = t >> 6, c = t & 63;
    if (n >= N_NODES) return;
    const float* xr = x + n * IN_C;
    float acc = 0.f;
#pragma unroll
    for (int k = 0; k < IN_C; ++k) acc += xr[k] * W[k * H1 + c];
    hw[t] = acc;
}

// in = pre-activation layer-1 output; ReLU on load.
__global__ void k_gemm2(const float* __restrict__ in, const float* __restrict__ W,
                        float* __restrict__ hw) {
    int t = blockIdx.x * blockDim.x + threadIdx.x;
    int n = t >> 6, c = t & 63;
    if (n >= N_NODES) return;
    const float* r = in + n * H1;
    float acc = 0.f;
#pragma unroll
    for (int k = 0; k < H1; ++k) acc += fmaxf(r[k], 0.f) * W[k * H2 + c];
    hw[t] = acc;
}

// ---------------- aggregation (gather, 1 wave per node) ----------------
// out[n][c] = b[c] + hw[n][c]*dinv[n]^2 + sum_{s in in(n)} hw[s][c]*dinv[s]*dinv[n]

__global__ void __launch_bounds__(256) k_gather(
    const int* __restrict__ rowoff, const int* __restrict__ src_sorted,
    const float* __restrict__ dinv, const float* __restrict__ hw,
    const float* __restrict__ b, float* __restrict__ out)
{
    int n = (int)((blockIdx.x * blockDim.x + threadIdx.x) >> 6);
    int lane = threadIdx.x & 63;
    if (n >= N_NODES) return;
    int beg = rowoff[n], end = rowoff[n + 1];
    float di = dinv[n];
    float acc = b[lane] + hw[n * 64 + lane] * di * di;
    int i = beg;
    for (; i + 4 <= end; i += 4) {
        int s0 = src_sorted[i + 0];
        int s1 = src_sorted[i + 1];
        int s2 = src_sorted[i + 2];
        int s3 = src_sorted[i + 3];
        float w0 = dinv[s0] * di, w1 = dinv[s1] * di;
        float w2 = dinv[s2] * di, w3 = dinv[s3] * di;
        float h0 = hw[s0 * 64 + lane];
        float h1 = hw[s1 * 64 + lane];
        float h2 = hw[s2 * 64 + lane];
        float h3 = hw[s3 * 64 + lane];
        acc += h0 * w0;
        acc += h1 * w1;
        acc += h2 * w2;
        acc += h3 * w3;
    }
    for (; i < end; ++i) {
        int s = src_sorted[i];
        acc += hw[s * 64 + lane] * (dinv[s] * di);
    }
    out[n * 64 + lane] = acc;
}

// ---------------- pooling ----------------

__global__ void k_pool_zero(float* __restrict__ pool, float* __restrict__ cnt) {
    int i = blockIdx.x * blockDim.x + threadIdx.x;
    if (i < N_GRAPHS * H2) pool[i] = 0.f;
    if (i < N_GRAPHS) cnt[i] = 0.f;
}

__global__ void k_count(const int* __restrict__ batch, float* __restrict__ cnt) {
    int n = blockIdx.x * blockDim.x + threadIdx.x;
    if (n < N_NODES) atomicAdd(&cnt[batch[n]], 1.0f);
}

__global__ void k_pool(const int* __restrict__ batch, const float* __restrict__ h,
                       float* __restrict__ pool) {
    int t = blockIdx.x * blockDim.x + threadIdx.x;
    int n = t >> 6, c = t & 63;
    if (n >= N_NODES) return;
    atomicAdd(&pool[batch[n] * H2 + c], fmaxf(h[t], 0.f));
}

// ---------------- MLP head (one block per graph) ----------------

__global__ void __launch_bounds__(128)
k_mlp(const float* __restrict__ pool, const float* __restrict__ cnt,
      const float* __restrict__ Wf1, const float* __restrict__ bf1,
      const float* __restrict__ Wf2, const float* __restrict__ bf2,
      float* __restrict__ out) {
    int g = blockIdx.x;
    int tid = threadIdx.x;
    __shared__ float p[H2];
    __shared__ float tbuf[H3];
    float inv = 1.0f / fmaxf(cnt[g], 1.0f);
    if (tid < H2) p[tid] = pool[g * H2 + tid] * inv;
    __syncthreads();
    {
        float acc = bf1[tid];
#pragma unroll
        for (int k = 0; k < H2; ++k) acc += p[k] * Wf1[k * H3 + tid];
        tbuf[tid] = acc;   // no ReLU between Wf1 and Wf2 (matches reference)
    }
    __syncthreads();
    if (tid < OUT_C) {
        float acc = bf2[tid];
#pragma unroll
        for (int m = 0; m < H3; ++m) acc += tbuf[m] * Wf2[m * OUT_C + tid];
        out[g * OUT_C + tid] = acc;
    }
}

// ---------------- launch ----------------

extern "C" void kernel_launch(void* const* d_in, const int* in_sizes, int n_in,
                              void* d_out, int out_size, void* d_ws, size_t ws_size,
                              hipStream_t stream) {
    const float* x    = (const float*)d_in[0];
    const int*   ei   = (const int*)  d_in[1];   // [2, E]
    const int*   batch= (const int*)  d_in[2];
    const float* W1   = (const float*)d_in[3];
    const float* b1   = (const float*)d_in[4];
    const float* W2   = (const float*)d_in[5];
    const float* b2   = (const float*)d_in[6];
    const float* Wf1  = (const float*)d_in[7];
    const float* bf1  = (const float*)d_in[8];
    const float* Wf2  = (const float*)d_in[9];
    const float* bf2  = (const float*)d_in[10];
    float* out = (float*)d_out;

    const int* src = ei;            // edge_index[0]
    const int* dst = ei + N_EDGES;  // edge_index[1]

    char* ws = (char*)d_ws;
    size_t off = 0;
    auto alloc = [&](size_t bytes) {
        char* p = ws + off;
        off += (bytes + 255) & ~size_t(255);
        return p;
    };
    float* dinv       = (float*)alloc(N_NODES * sizeof(float));
    int*   cnt_in     = (int*)  alloc(N_NODES * sizeof(int));
    int*   fill       = (int*)  alloc(N_NODES * sizeof(int));
    int*   rowoff     = (int*)  alloc((N_NODES + 1) * sizeof(int));
    int*   src_sorted = (int*)  alloc((size_t)N_EDGES * sizeof(int));
    float* bufA       = (float*)alloc((size_t)N_NODES * 64 * sizeof(float));
    float* bufB       = (float*)alloc((size_t)N_NODES * 64 * sizeof(float));
    float* pool       = (float*)alloc(N_GRAPHS * H2 * sizeof(float));
    float* gcnt       = (float*)alloc(N_GRAPHS * sizeof(float));
    (void)ws_size;

    const int BLK = 256;
    int gN  = (N_NODES + BLK - 1) / BLK;
    int gE  = (N_EDGES + BLK - 1) / BLK;
    int gNC = (N_NODES * 64 + BLK - 1) / BLK;   // thread per (node,channel)
    int gNW = (N_NODES * 64 + BLK - 1) / BLK;   // wave per node (64 lanes)

    // CSR build + norms
    k_zero2  <<<gN, BLK, 0, stream>>>(cnt_in, fill);
    k_hist   <<<gE, BLK, 0, stream>>>(dst, cnt_in);
    k_dinv   <<<gN, BLK, 0, stream>>>(cnt_in, dinv);
    k_scan   <<<1, 1024, 0, stream>>>(cnt_in, rowoff);
    k_scatter<<<gE, BLK, 0, stream>>>(src, dst, rowoff, fill, src_sorted);

    // layer 1
    k_gemm1 <<<gNC, BLK, 0, stream>>>(x, W1, bufA);
    k_gather<<<gNW, BLK, 0, stream>>>(rowoff, src_sorted, dinv, bufA, b1, bufB);

    // layer 2
    k_gemm2 <<<gNC, BLK, 0, stream>>>(bufB, W2, bufA);
    k_gather<<<gNW, BLK, 0, stream>>>(rowoff, src_sorted, dinv, bufA, b2, bufB);

    // global mean pool of relu(out2)
    int gP = (N_GRAPHS * H2 + BLK - 1) / BLK;
    k_pool_zero<<<gP, BLK, 0, stream>>>(pool, gcnt);
    k_count    <<<gN, BLK, 0, stream>>>(batch, gcnt);
    k_pool     <<<gNC, BLK, 0, stream>>>(batch, bufB, pool);

    // MLP head
    k_mlp<<<N_GRAPHS, 128, 0, stream>>>(pool, gcnt, Wf1, bf1, Wf2, bf2, out);
}

// Round 3
// 261.156 us; speedup vs baseline: 3.5578x; 1.8632x over previous
//
#include <hip/hip_runtime.h>

#define N_NODES   50000
#define N_EDGES   1600000
#define N_GRAPHS  512
#define IN_C      16
#define H1        64
#define H2        64
#define H3        128
#define OUT_C     10

#define NBKT      196      // ceil(50000/256): bucket = dst>>8
#define CHUNK     2048     // edges per bin-pass block
#define CAP       12288    // max edges per bucket (mean 8192, sigma ~90)

typedef unsigned int  uint;
typedef unsigned short ushort;

// ---------------- zero ----------------

__global__ void k_zero(int* __restrict__ bktcnt, float* __restrict__ pool,
                       float* __restrict__ gcnt) {
    int i = blockIdx.x * blockDim.x + threadIdx.x;
    if (i < NBKT) bktcnt[i] = 0;
    if (i < N_GRAPHS * H2) pool[i] = 0.f;
    if (i < N_GRAPHS) gcnt[i] = 0.f;
}

// ---------------- bucket histogram (LDS-staged) ----------------

__global__ void __launch_bounds__(256) k_bkt_hist(const int* __restrict__ dst,
                                                  int* __restrict__ bktcnt) {
    __shared__ int lc[NBKT];
    int tid = threadIdx.x;
    for (int i = tid; i < NBKT; i += 256) lc[i] = 0;
    __syncthreads();
    long long e0 = (long long)blockIdx.x * CHUNK;
    int cn = (int)((N_EDGES - e0) < CHUNK ? (N_EDGES - e0) : CHUNK);
    for (int i = tid; i < cn; i += 256)
        atomicAdd(&lc[((uint)dst[e0 + i]) >> 8], 1);
    __syncthreads();
    for (int i = tid; i < NBKT; i += 256)
        if (lc[i]) atomicAdd(&bktcnt[i], lc[i]);
}

// ---------------- bucket scan (1 block) ----------------

__global__ void __launch_bounds__(256) k_bkt_scan(const int* __restrict__ bktcnt,
                                                  int* __restrict__ bkt_base,
                                                  int* __restrict__ bkt_fill) {
    __shared__ int tmp[256];
    int tid = threadIdx.x;
    int v = (tid < NBKT) ? bktcnt[tid] : 0;
    tmp[tid] = v;
    __syncthreads();
    for (int s = 1; s < 256; s <<= 1) {
        int t = (tid >= s) ? tmp[tid - s] : 0;
        __syncthreads();
        tmp[tid] += t;
        __syncthreads();
    }
    if (tid < NBKT) { bkt_base[tid] = tmp[tid] - v; bkt_fill[tid] = 0; }
    if (tid == 255) bkt_base[NBKT] = tmp[255];   // total = N_EDGES
}

// ---------------- bin edges by bucket (locality-staged scatter) ----------------

__global__ void __launch_bounds__(256) k_binB(const int* __restrict__ src,
                                              const int* __restrict__ dst,
                                              const int* __restrict__ bkt_base,
                                              int* __restrict__ bkt_fill,
                                              uint* __restrict__ bucket_edges) {
    __shared__ int  lcnt[NBKT];
    __shared__ int  loff[NBKT];
    __shared__ int  gbase[NBKT];
    __shared__ int  tmp[256];
    __shared__ uint stage[CHUNK];
    int tid = threadIdx.x;
    long long e0 = (long long)blockIdx.x * CHUNK;
    int cn = (int)((N_EDGES - e0) < CHUNK ? (N_EDGES - e0) : CHUNK);

    for (int i = tid; i < NBKT; i += 256) lcnt[i] = 0;
    __syncthreads();

    uint pk[8]; int rk[8]; int bkr[8];
#pragma unroll
    for (int k = 0; k < 8; ++k) {
        int i = k * 256 + tid;
        pk[k] = 0; rk[k] = -1; bkr[k] = 0;
        if (i < cn) {
            int e = (int)e0 + i;
            uint d = (uint)dst[e], s = (uint)src[e];
            pk[k] = (d << 16) | s;
            bkr[k] = (int)(d >> 8);
            rk[k] = atomicAdd(&lcnt[bkr[k]], 1);
        }
    }
    __syncthreads();

    // exclusive scan of lcnt
    int v = (tid < NBKT) ? lcnt[tid] : 0;
    tmp[tid] = v;
    __syncthreads();
    for (int s = 1; s < 256; s <<= 1) {
        int t = (tid >= s) ? tmp[tid - s] : 0;
        __syncthreads();
        tmp[tid] += t;
        __syncthreads();
    }
    if (tid < NBKT) loff[tid] = tmp[tid] - v;
    if (tid < NBKT && v > 0) gbase[tid] = atomicAdd(&bkt_fill[tid], v);
    __syncthreads();

    // stage locally sorted by bucket
#pragma unroll
    for (int k = 0; k < 8; ++k)
        if (rk[k] >= 0) stage[loff[bkr[k]] + rk[k]] = pk[k];
    __syncthreads();

    // write: consecutive i -> runs within the same bucket window
    for (int i = tid; i < cn; i += 256) {
        uint p = stage[i];
        int b = (int)(p >> 24);
        int dest = bkt_base[b] + gbase[b] + (i - loff[b]);
        bucket_edges[dest] = p;
    }
}

// ---------------- per-bucket CSR finalize ----------------
// writes rowoff, dinv, src_sorted (u16) — all scatters confined to LDS

__global__ void __launch_bounds__(256) k_bkt_csr(const int* __restrict__ bkt_base,
                                                 const uint* __restrict__ bucket_edges,
                                                 int* __restrict__ rowoff,
                                                 float* __restrict__ dinv,
                                                 ushort* __restrict__ src_sorted) {
    __shared__ int ncnt[256];
    __shared__ int noff[256];
    __shared__ int tmp[256];
    __shared__ ushort su[CAP];
    int b = blockIdx.x, tid = threadIdx.x;
    int base = bkt_base[b];
    int cntE = bkt_base[b + 1] - base;

    ncnt[tid] = 0;
    __syncthreads();
    for (int i = tid; i < cntE; i += 256) {
        uint p = bucket_edges[base + i];
        atomicAdd(&ncnt[(p >> 16) & 255], 1);
    }
    __syncthreads();

    int v = ncnt[tid];
    tmp[tid] = v;
    __syncthreads();
    for (int s = 1; s < 256; s <<= 1) {
        int t = (tid >= s) ? tmp[tid - s] : 0;
        __syncthreads();
        tmp[tid] += t;
        __syncthreads();
    }
    noff[tid] = tmp[tid] - v;

    int n = b * 256 + tid;
    if (n < N_NODES) {
        rowoff[n] = base + (tmp[tid] - v);
        dinv[n] = rsqrtf((float)(v + 1));
    }
    if (b == 0 && tid == 0) rowoff[N_NODES] = N_EDGES;

    ncnt[tid] = 0;
    __syncthreads();
    for (int i = tid; i < cntE; i += 256) {
        uint p = bucket_edges[base + i];
        int l = (p >> 16) & 255;
        int r = atomicAdd(&ncnt[l], 1);
        int pos = noff[l] + r;
        if (pos < CAP) su[pos] = (ushort)(p & 0xFFFF);
    }
    __syncthreads();
    for (int i = tid; i < cntE; i += 256)
        src_sorted[base + i] = su[i];
}

// ---------------- layer GEMMs ----------------

__global__ void k_gemm1(const float* __restrict__ x, const float* __restrict__ W,
                        float* __restrict__ hw) {
    int t = blockIdx.x * blockDim.x + threadIdx.x;
    int n = t >> 6, c = t & 63;
    if (n >= N_NODES) return;
    const float* xr = x + n * IN_C;
    float acc = 0.f;
#pragma unroll
    for (int k = 0; k < IN_C; ++k) acc += xr[k] * W[k * H1 + c];
    hw[t] = acc;
}

__global__ void k_gemm2(const float* __restrict__ in, const float* __restrict__ W,
                        float* __restrict__ hw) {
    int t = blockIdx.x * blockDim.x + threadIdx.x;
    int n = t >> 6, c = t & 63;
    if (n >= N_NODES) return;
    const float* r = in + n * H1;
    float acc = 0.f;
#pragma unroll
    for (int k = 0; k < H1; ++k) acc += fmaxf(r[k], 0.f) * W[k * H2 + c];
    hw[t] = acc;
}

// ---------------- aggregation (gather, wave per node, readlane broadcast) ----------------

__global__ void __launch_bounds__(256) k_gather(
    const int* __restrict__ rowoff, const ushort* __restrict__ src_sorted,
    const float* __restrict__ dinv, const float* __restrict__ hw,
    const float* __restrict__ b, float* __restrict__ out)
{
    int lane = threadIdx.x & 63;
    int n = __builtin_amdgcn_readfirstlane(blockIdx.x * 4 + (threadIdx.x >> 6));
    if (n >= N_NODES) return;
    int beg = rowoff[n], end = rowoff[n + 1];
    float di = dinv[n];
    float a0 = b[lane] + hw[n * 64 + lane] * di * di;
    float a1 = 0.f, a2 = 0.f, a3 = 0.f;

    for (int basei = beg; basei < end; basei += 64) {
        int rem = end - basei;
        int m = rem < 64 ? rem : 64;
        int su = 0;
        if (lane < m) su = (int)src_sorted[basei + lane];
        float wu = (lane < m) ? dinv[su] * di : 0.f;
        int wub = __float_as_int(wu);
        int j = 0;
        for (; j + 4 <= m; j += 4) {
            int s0 = __builtin_amdgcn_readlane(su, j);
            int s1 = __builtin_amdgcn_readlane(su, j + 1);
            int s2 = __builtin_amdgcn_readlane(su, j + 2);
            int s3 = __builtin_amdgcn_readlane(su, j + 3);
            float w0 = __int_as_float(__builtin_amdgcn_readlane(wub, j));
            float w1 = __int_as_float(__builtin_amdgcn_readlane(wub, j + 1));
            float w2 = __int_as_float(__builtin_amdgcn_readlane(wub, j + 2));
            float w3 = __int_as_float(__builtin_amdgcn_readlane(wub, j + 3));
            a0 += hw[s0 * 64 + lane] * w0;
            a1 += hw[s1 * 64 + lane] * w1;
            a2 += hw[s2 * 64 + lane] * w2;
            a3 += hw[s3 * 64 + lane] * w3;
        }
        for (; j < m; ++j) {
            int s = __builtin_amdgcn_readlane(su, j);
            float w = __int_as_float(__builtin_amdgcn_readlane(wub, j));
            a1 += hw[s * 64 + lane] * w;
        }
    }
    out[n * 64 + lane] = (a0 + a1) + (a2 + a3);
}

// ---------------- fused pool + count (batch is sorted) ----------------
// wave per 64 consecutive nodes; flush one atomic row per graph-run

__global__ void __launch_bounds__(256) k_pool2(const int* __restrict__ batch,
                                               const float* __restrict__ h,
                                               float* __restrict__ pool,
                                               float* __restrict__ gcnt) {
    int wave = (blockIdx.x * blockDim.x + threadIdx.x) >> 6;
    int lane = threadIdx.x & 63;
    int n0 = wave * 64;
    if (n0 >= N_NODES) return;
    int nend = n0 + 64 < N_NODES ? n0 + 64 : N_NODES;
    int g = batch[n0];
    float acc = 0.f, c = 0.f;
    for (int n = n0; n < nend; ++n) {
        int gn = batch[n];
        if (gn != g) {
            atomicAdd(&pool[g * 64 + lane], acc);
            if (lane == 0) atomicAdd(&gcnt[g], c);
            acc = 0.f; c = 0.f; g = gn;
        }
        acc += fmaxf(h[n * 64 + lane], 0.f);
        c += 1.f;
    }
    atomicAdd(&pool[g * 64 + lane], acc);
    if (lane == 0) atomicAdd(&gcnt[g], c);
}

// ---------------- MLP head ----------------

__global__ void __launch_bounds__(128)
k_mlp(const float* __restrict__ pool, const float* __restrict__ cnt,
      const float* __restrict__ Wf1, const float* __restrict__ bf1,
      const float* __restrict__ Wf2, const float* __restrict__ bf2,
      float* __restrict__ out) {
    int g = blockIdx.x;
    int tid = threadIdx.x;
    __shared__ float p[H2];
    __shared__ float tbuf[H3];
    float inv = 1.0f / fmaxf(cnt[g], 1.0f);
    if (tid < H2) p[tid] = pool[g * H2 + tid] * inv;
    __syncthreads();
    {
        float acc = bf1[tid];
#pragma unroll
        for (int k = 0; k < H2; ++k) acc += p[k] * Wf1[k * H3 + tid];
        tbuf[tid] = acc;   // no ReLU between Wf1 and Wf2 (matches reference)
    }
    __syncthreads();
    if (tid < OUT_C) {
        float acc = bf2[tid];
#pragma unroll
        for (int m = 0; m < H3; ++m) acc += tbuf[m] * Wf2[m * OUT_C + tid];
        out[g * OUT_C + tid] = acc;
    }
}

// ---------------- launch ----------------

extern "C" void kernel_launch(void* const* d_in, const int* in_sizes, int n_in,
                              void* d_out, int out_size, void* d_ws, size_t ws_size,
                              hipStream_t stream) {
    const float* x    = (const float*)d_in[0];
    const int*   ei   = (const int*)  d_in[1];
    const int*   batch= (const int*)  d_in[2];
    const float* W1   = (const float*)d_in[3];
    const float* b1   = (const float*)d_in[4];
    const float* W2   = (const float*)d_in[5];
    const float* b2   = (const float*)d_in[6];
    const float* Wf1  = (const float*)d_in[7];
    const float* bf1  = (const float*)d_in[8];
    const float* Wf2  = (const float*)d_in[9];
    const float* bf2  = (const float*)d_in[10];
    float* out = (float*)d_out;

    const int* src = ei;
    const int* dst = ei + N_EDGES;

    char* ws = (char*)d_ws;
    size_t off = 0;
    auto alloc = [&](size_t bytes) {
        char* p = ws + off;
        off += (bytes + 255) & ~size_t(255);
        return p;
    };
    float*  dinv       = (float*) alloc(N_NODES * sizeof(float));
    int*    rowoff     = (int*)   alloc((N_NODES + 1) * sizeof(int));
    ushort* src_sorted = (ushort*)alloc((size_t)N_EDGES * sizeof(ushort));
    int*    bktcnt     = (int*)   alloc(NBKT * sizeof(int));
    int*    bkt_base   = (int*)   alloc((NBKT + 1) * sizeof(int));
    int*    bkt_fill   = (int*)   alloc(NBKT * sizeof(int));
    float*  pool       = (float*) alloc(N_GRAPHS * H2 * sizeof(float));
    float*  gcnt       = (float*) alloc(N_GRAPHS * sizeof(float));
    float*  bufA       = (float*) alloc((size_t)N_NODES * 64 * sizeof(float));
    float*  bufB       = (float*) alloc((size_t)N_NODES * 64 * sizeof(float));
    uint*   bucket_edges = (uint*)bufB;   // alias: dead before first bufB write
    (void)ws_size;

    const int BLK = 256;
    int gN  = (N_NODES + BLK - 1) / BLK;
    int gE  = (N_EDGES + CHUNK - 1) / CHUNK;             // 782
    int gNC = (N_NODES * 64 + BLK - 1) / BLK;
    int gNW = (N_NODES + 3) / 4;                         // wave per node, 4/block
    int gZ  = (N_GRAPHS * H2 + BLK - 1) / BLK;
    int gPW = ((N_NODES + 63) / 64 * 64 + BLK - 1) / BLK; // wave per 64 nodes

    // CSR build
    k_zero    <<<gZ, BLK, 0, stream>>>(bktcnt, pool, gcnt);
    k_bkt_hist<<<gE, BLK, 0, stream>>>(dst, bktcnt);
    k_bkt_scan<<<1,  BLK, 0, stream>>>(bktcnt, bkt_base, bkt_fill);
    k_binB    <<<gE, BLK, 0, stream>>>(src, dst, bkt_base, bkt_fill, bucket_edges);
    k_bkt_csr <<<NBKT, BLK, 0, stream>>>(bkt_base, bucket_edges, rowoff, dinv, src_sorted);

    // layer 1
    k_gemm1 <<<gNC, BLK, 0, stream>>>(x, W1, bufA);
    k_gather<<<gNW, BLK, 0, stream>>>(rowoff, src_sorted, dinv, bufA, b1, bufB);

    // layer 2
    k_gemm2 <<<gNC, BLK, 0, stream>>>(bufB, W2, bufA);
    k_gather<<<gNW, BLK, 0, stream>>>(rowoff, src_sorted, dinv, bufA, b2, bufB);

    // pool + head
    k_pool2<<<gPW, BLK, 0, stream>>>(batch, bufB, pool, gcnt);
    k_mlp  <<<N_GRAPHS, 128, 0, stream>>>(pool, gcnt, Wf1, bf1, Wf2, bf2, out);
}

// Round 4
// 219.405 us; speedup vs baseline: 4.2349x; 1.1903x over previous
//
#include <hip/hip_runtime.h>

#define N_NODES   50000
#define N_EDGES   1600000
#define N_GRAPHS  512
#define IN_C      16
#define H1        64
#define H2        64
#define H3        128
#define OUT_C     10

#define NBKT      196      // ceil(50000/256): bucket = dst>>8
#define CHUNK     2048     // edges per bin-pass block
#define CAP       12288    // max edges per bucket (mean 8192)

typedef unsigned int  uint;
typedef unsigned short ushort;

// ---------------- zero ----------------

__global__ void k_zero(int* __restrict__ bktcnt, float* __restrict__ pool,
                       float* __restrict__ gcnt) {
    int i = blockIdx.x * blockDim.x + threadIdx.x;
    if (i < NBKT) bktcnt[i] = 0;
    if (i < N_GRAPHS * H2) pool[i] = 0.f;
    if (i < N_GRAPHS) gcnt[i] = 0.f;
}

// ---------------- bucket histogram (LDS-staged) ----------------

__global__ void __launch_bounds__(256) k_bkt_hist(const int* __restrict__ dst,
                                                  int* __restrict__ bktcnt) {
    __shared__ int lc[NBKT];
    int tid = threadIdx.x;
    for (int i = tid; i < NBKT; i += 256) lc[i] = 0;
    __syncthreads();
    long long e0 = (long long)blockIdx.x * CHUNK;
    int cn = (int)((N_EDGES - e0) < CHUNK ? (N_EDGES - e0) : CHUNK);
    for (int i = tid; i < cn; i += 256)
        atomicAdd(&lc[((uint)dst[e0 + i]) >> 8], 1);
    __syncthreads();
    for (int i = tid; i < NBKT; i += 256)
        if (lc[i]) atomicAdd(&bktcnt[i], lc[i]);
}

// ---------------- bucket scan (1 block) ----------------

__global__ void __launch_bounds__(256) k_bkt_scan(const int* __restrict__ bktcnt,
                                                  int* __restrict__ bkt_base,
                                                  int* __restrict__ bkt_fill) {
    __shared__ int tmp[256];
    int tid = threadIdx.x;
    int v = (tid < NBKT) ? bktcnt[tid] : 0;
    tmp[tid] = v;
    __syncthreads();
    for (int s = 1; s < 256; s <<= 1) {
        int t = (tid >= s) ? tmp[tid - s] : 0;
        __syncthreads();
        tmp[tid] += t;
        __syncthreads();
    }
    if (tid < NBKT) { bkt_base[tid] = tmp[tid] - v; bkt_fill[tid] = 0; }
    if (tid == 255) bkt_base[NBKT] = tmp[255];   // total = N_EDGES
}

// ---------------- bin edges by bucket (locality-staged scatter) ----------------

__global__ void __launch_bounds__(256) k_binB(const int* __restrict__ src,
                                              const int* __restrict__ dst,
                                              const int* __restrict__ bkt_base,
                                              int* __restrict__ bkt_fill,
                                              uint* __restrict__ bucket_edges) {
    __shared__ int  lcnt[NBKT];
    __shared__ int  loff[NBKT];
    __shared__ int  gbase[NBKT];
    __shared__ int  tmp[256];
    __shared__ uint stage[CHUNK];
    int tid = threadIdx.x;
    long long e0 = (long long)blockIdx.x * CHUNK;
    int cn = (int)((N_EDGES - e0) < CHUNK ? (N_EDGES - e0) : CHUNK);

    for (int i = tid; i < NBKT; i += 256) lcnt[i] = 0;
    __syncthreads();

    uint pk[8]; int rk[8]; int bkr[8];
#pragma unroll
    for (int k = 0; k < 8; ++k) {
        int i = k * 256 + tid;
        pk[k] = 0; rk[k] = -1; bkr[k] = 0;
        if (i < cn) {
            int e = (int)e0 + i;
            uint d = (uint)dst[e], s = (uint)src[e];
            pk[k] = (d << 16) | s;
            bkr[k] = (int)(d >> 8);
            rk[k] = atomicAdd(&lcnt[bkr[k]], 1);
        }
    }
    __syncthreads();

    int v = (tid < NBKT) ? lcnt[tid] : 0;
    tmp[tid] = v;
    __syncthreads();
    for (int s = 1; s < 256; s <<= 1) {
        int t = (tid >= s) ? tmp[tid - s] : 0;
        __syncthreads();
        tmp[tid] += t;
        __syncthreads();
    }
    if (tid < NBKT) loff[tid] = tmp[tid] - v;
    if (tid < NBKT && v > 0) gbase[tid] = atomicAdd(&bkt_fill[tid], v);
    __syncthreads();

#pragma unroll
    for (int k = 0; k < 8; ++k)
        if (rk[k] >= 0) stage[loff[bkr[k]] + rk[k]] = pk[k];
    __syncthreads();

    for (int i = tid; i < cn; i += 256) {
        uint p = stage[i];
        int b = (int)(p >> 24);
        int dest = bkt_base[b] + gbase[b] + (i - loff[b]);
        bucket_edges[dest] = p;
    }
}

// ---------------- per-bucket CSR finalize ----------------

__global__ void __launch_bounds__(256) k_bkt_csr(const int* __restrict__ bkt_base,
                                                 const uint* __restrict__ bucket_edges,
                                                 int* __restrict__ rowoff,
                                                 float* __restrict__ dinv,
                                                 ushort* __restrict__ src_sorted) {
    __shared__ int ncnt[256];
    __shared__ int noff[256];
    __shared__ int tmp[256];
    __shared__ ushort su[CAP];
    int b = blockIdx.x, tid = threadIdx.x;
    int base = bkt_base[b];
    int cntE = bkt_base[b + 1] - base;

    ncnt[tid] = 0;
    __syncthreads();
    for (int i = tid; i < cntE; i += 256) {
        uint p = bucket_edges[base + i];
        atomicAdd(&ncnt[(p >> 16) & 255], 1);
    }
    __syncthreads();

    int v = ncnt[tid];
    tmp[tid] = v;
    __syncthreads();
    for (int s = 1; s < 256; s <<= 1) {
        int t = (tid >= s) ? tmp[tid - s] : 0;
        __syncthreads();
        tmp[tid] += t;
        __syncthreads();
    }
    noff[tid] = tmp[tid] - v;

    int n = b * 256 + tid;
    if (n < N_NODES) {
        rowoff[n] = base + (tmp[tid] - v);
        dinv[n] = rsqrtf((float)(v + 1));
    }
    if (b == 0 && tid == 0) rowoff[N_NODES] = N_EDGES;

    ncnt[tid] = 0;
    __syncthreads();
    for (int i = tid; i < cntE; i += 256) {
        uint p = bucket_edges[base + i];
        int l = (p >> 16) & 255;
        int r = atomicAdd(&ncnt[l], 1);
        int pos = noff[l] + r;
        if (pos < CAP) su[pos] = (ushort)(p & 0xFFFF);
    }
    __syncthreads();
    for (int i = tid; i < cntE; i += 256)
        src_sorted[base + i] = su[i];
}

// ---------------- LDS-tiled GEMM: out[n][0:64] = act(in[n][:]) @ W ----------------
// block = 256 threads = 32 nodes x 8 channel-groups; W staged in LDS.

template<int INC, bool RELU>
__global__ void __launch_bounds__(256) k_gemm(const float* __restrict__ in,
                                              const float* __restrict__ W,
                                              float* __restrict__ out) {
    __shared__ float Wl[INC * 64];
    int tid = threadIdx.x;
#pragma unroll
    for (int i = tid; i < INC * 16; i += 256)
        ((float4*)Wl)[i] = ((const float4*)W)[i];
    __syncthreads();

    int n = blockIdx.x * 32 + (tid >> 3);
    int c0 = (tid & 7) * 8;
    if (n >= N_NODES) return;

    const float4* row = (const float4*)(in + (size_t)n * INC);
    float acc[8];
#pragma unroll
    for (int j = 0; j < 8; ++j) acc[j] = 0.f;

#pragma unroll 4
    for (int kb = 0; kb < INC / 4; ++kb) {
        float4 r = row[kb];
        if (RELU) {
            r.x = fmaxf(r.x, 0.f); r.y = fmaxf(r.y, 0.f);
            r.z = fmaxf(r.z, 0.f); r.w = fmaxf(r.w, 0.f);
        }
        const float* wr = &Wl[(kb * 4) * 64 + c0];
        float rk[4] = {r.x, r.y, r.z, r.w};
#pragma unroll
        for (int k = 0; k < 4; ++k) {
            float4 w0 = *(const float4*)(wr + k * 64);
            float4 w1 = *(const float4*)(wr + k * 64 + 4);
            acc[0] += rk[k] * w0.x;  acc[1] += rk[k] * w0.y;
            acc[2] += rk[k] * w0.z;  acc[3] += rk[k] * w0.w;
            acc[4] += rk[k] * w1.x;  acc[5] += rk[k] * w1.y;
            acc[6] += rk[k] * w1.z;  acc[7] += rk[k] * w1.w;
        }
    }
    float4 o0 = {acc[0], acc[1], acc[2], acc[3]};
    float4 o1 = {acc[4], acc[5], acc[6], acc[7]};
    *(float4*)(out + (size_t)n * 64 + c0)     = o0;
    *(float4*)(out + (size_t)n * 64 + c0 + 4) = o1;
}

// ---------------- aggregation (gather, wave per node, readlane broadcast) ----------------

__global__ void __launch_bounds__(256) k_gather(
    const int* __restrict__ rowoff, const ushort* __restrict__ src_sorted,
    const float* __restrict__ dinv, const float* __restrict__ hw,
    const float* __restrict__ b, float* __restrict__ out)
{
    int lane = threadIdx.x & 63;
    int n = __builtin_amdgcn_readfirstlane(blockIdx.x * 4 + (threadIdx.x >> 6));
    if (n >= N_NODES) return;
    int beg = rowoff[n], end = rowoff[n + 1];
    float di = dinv[n];
    float a0 = b[lane] + hw[n * 64 + lane] * di * di;
    float a1 = 0.f, a2 = 0.f, a3 = 0.f;

    for (int basei = beg; basei < end; basei += 64) {
        int rem = end - basei;
        int m = rem < 64 ? rem : 64;
        int su = 0;
        if (lane < m) su = (int)src_sorted[basei + lane];
        float wu = (lane < m) ? dinv[su] * di : 0.f;
        int wub = __float_as_int(wu);
        int j = 0;
        for (; j + 4 <= m; j += 4) {
            int s0 = __builtin_amdgcn_readlane(su, j);
            int s1 = __builtin_amdgcn_readlane(su, j + 1);
            int s2 = __builtin_amdgcn_readlane(su, j + 2);
            int s3 = __builtin_amdgcn_readlane(su, j + 3);
            float w0 = __int_as_float(__builtin_amdgcn_readlane(wub, j));
            float w1 = __int_as_float(__builtin_amdgcn_readlane(wub, j + 1));
            float w2 = __int_as_float(__builtin_amdgcn_readlane(wub, j + 2));
            float w3 = __int_as_float(__builtin_amdgcn_readlane(wub, j + 3));
            a0 += hw[s0 * 64 + lane] * w0;
            a1 += hw[s1 * 64 + lane] * w1;
            a2 += hw[s2 * 64 + lane] * w2;
            a3 += hw[s3 * 64 + lane] * w3;
        }
        for (; j < m; ++j) {
            int s = __builtin_amdgcn_readlane(su, j);
            float w = __int_as_float(__builtin_amdgcn_readlane(wub, j));
            a1 += hw[s * 64 + lane] * w;
        }
    }
    out[n * 64 + lane] = (a0 + a1) + (a2 + a3);
}

// ---------------- fused pool + count (batch is sorted) ----------------

__global__ void __launch_bounds__(256) k_pool2(const int* __restrict__ batch,
                                               const float* __restrict__ h,
                                               float* __restrict__ pool,
                                               float* __restrict__ gcnt) {
    int wave = (blockIdx.x * blockDim.x + threadIdx.x) >> 6;
    int lane = threadIdx.x & 63;
    int n0 = wave * 64;
    if (n0 >= N_NODES) return;
    int nend = n0 + 64 < N_NODES ? n0 + 64 : N_NODES;
    int g = batch[n0];
    float acc = 0.f, c = 0.f;
    for (int n = n0; n < nend; ++n) {
        int gn = batch[n];
        if (gn != g) {
            atomicAdd(&pool[g * 64 + lane], acc);
            if (lane == 0) atomicAdd(&gcnt[g], c);
            acc = 0.f; c = 0.f; g = gn;
        }
        acc += fmaxf(h[n * 64 + lane], 0.f);
        c += 1.f;
    }
    atomicAdd(&pool[g * 64 + lane], acc);
    if (lane == 0) atomicAdd(&gcnt[g], c);
}

// ---------------- MLP head ----------------

__global__ void __launch_bounds__(128)
k_mlp(const float* __restrict__ pool, const float* __restrict__ cnt,
      const float* __restrict__ Wf1, const float* __restrict__ bf1,
      const float* __restrict__ Wf2, const float* __restrict__ bf2,
      float* __restrict__ out) {
    int g = blockIdx.x;
    int tid = threadIdx.x;
    __shared__ float p[H2];
    __shared__ float tbuf[H3];
    float inv = 1.0f / fmaxf(cnt[g], 1.0f);
    if (tid < H2) p[tid] = pool[g * H2 + tid] * inv;
    __syncthreads();
    {
        float acc = bf1[tid];
#pragma unroll
        for (int k = 0; k < H2; ++k) acc += p[k] * Wf1[k * H3 + tid];
        tbuf[tid] = acc;   // no ReLU between Wf1 and Wf2 (matches reference)
    }
    __syncthreads();
    if (tid < OUT_C) {
        float acc = bf2[tid];
#pragma unroll
        for (int m = 0; m < H3; ++m) acc += tbuf[m] * Wf2[m * OUT_C + tid];
        out[g * OUT_C + tid] = acc;
    }
}

// ---------------- launch ----------------

extern "C" void kernel_launch(void* const* d_in, const int* in_sizes, int n_in,
                              void* d_out, int out_size, void* d_ws, size_t ws_size,
                              hipStream_t stream) {
    const float* x    = (const float*)d_in[0];
    const int*   ei   = (const int*)  d_in[1];
    const int*   batch= (const int*)  d_in[2];
    const float* W1   = (const float*)d_in[3];
    const float* b1   = (const float*)d_in[4];
    const float* W2   = (const float*)d_in[5];
    const float* b2   = (const float*)d_in[6];
    const float* Wf1  = (const float*)d_in[7];
    const float* bf1  = (const float*)d_in[8];
    const float* Wf2  = (const float*)d_in[9];
    const float* bf2  = (const float*)d_in[10];
    float* out = (float*)d_out;

    const int* src = ei;
    const int* dst = ei + N_EDGES;

    char* ws = (char*)d_ws;
    size_t off = 0;
    auto alloc = [&](size_t bytes) {
        char* p = ws + off;
        off += (bytes + 255) & ~size_t(255);
        return p;
    };
    float*  dinv       = (float*) alloc(N_NODES * sizeof(float));
    int*    rowoff     = (int*)   alloc((N_NODES + 1) * sizeof(int));
    ushort* src_sorted = (ushort*)alloc((size_t)N_EDGES * sizeof(ushort));
    int*    bktcnt     = (int*)   alloc(NBKT * sizeof(int));
    int*    bkt_base   = (int*)   alloc((NBKT + 1) * sizeof(int));
    int*    bkt_fill   = (int*)   alloc(NBKT * sizeof(int));
    float*  pool       = (float*) alloc(N_GRAPHS * H2 * sizeof(float));
    float*  gcnt       = (float*) alloc(N_GRAPHS * sizeof(float));
    float*  bufA       = (float*) alloc((size_t)N_NODES * 64 * sizeof(float));
    float*  bufB       = (float*) alloc((size_t)N_NODES * 64 * sizeof(float));
    uint*   bucket_edges = (uint*)bufB;   // alias: dead before first bufB write
    (void)ws_size;

    const int BLK = 256;
    int gE  = (N_EDGES + CHUNK - 1) / CHUNK;
    int gG  = (N_NODES + 31) / 32;                        // LDS-tiled gemm blocks
    int gNW = (N_NODES + 3) / 4;
    int gZ  = (N_GRAPHS * H2 + BLK - 1) / BLK;
    int gPW = ((N_NODES + 63) / 64 * 64 + BLK - 1) / BLK;

    // CSR build
    k_zero    <<<gZ, BLK, 0, stream>>>(bktcnt, pool, gcnt);
    k_bkt_hist<<<gE, BLK, 0, stream>>>(dst, bktcnt);
    k_bkt_scan<<<1,  BLK, 0, stream>>>(bktcnt, bkt_base, bkt_fill);
    k_binB    <<<gE, BLK, 0, stream>>>(src, dst, bkt_base, bkt_fill, bucket_edges);
    k_bkt_csr <<<NBKT, BLK, 0, stream>>>(bkt_base, bucket_edges, rowoff, dinv, src_sorted);

    // layer 1
    k_gemm<IN_C, false><<<gG, BLK, 0, stream>>>(x, W1, bufA);
    k_gather<<<gNW, BLK, 0, stream>>>(rowoff, src_sorted, dinv, bufA, b1, bufB);

    // layer 2
    k_gemm<H1, true><<<gG, BLK, 0, stream>>>(bufB, W2, bufA);
    k_gather<<<gNW, BLK, 0, stream>>>(rowoff, src_sorted, dinv, bufA, b2, bufB);

    // pool + head
    k_pool2<<<gPW, BLK, 0, stream>>>(batch, bufB, pool, gcnt);
    k_mlp  <<<N_GRAPHS, 128, 0, stream>>>(pool, gcnt, Wf1, bf1, Wf2, bf2, out);
}